// Round 3
// baseline (143.025 us; speedup 1.0000x reference)
//
#include <hip/hip_runtime.h>
#include <hip/hip_bf16.h>
#include <cmath>

#define BZ 8
#define PZ 8192
#define FZ 768
#define FI 256
#define M_TOTAL (BZ * PZ)   // 65536
#define BM 128
#define BN 128
#define BK 64
#define NKT (FZ / BK)       // 12

typedef __bf16 bf16_t;
typedef __bf16 bf16x8 __attribute__((ext_vector_type(8)));
typedef float f32x16 __attribute__((ext_vector_type(16)));

// ---------------- pack V_w / U_w into pair-interleaved bf16 ----------------
// packed row pr = 32*j + 16*u + r  ->  (u ? U_w : V_w)[16*j + r]
__global__ void pack_weights(const float* __restrict__ Vw,
                             const float* __restrict__ Uw,
                             bf16_t* __restrict__ Wc) {
    int pr = blockIdx.x;                 // 0..511
    int j = pr >> 5, u = (pr >> 4) & 1, r = pr & 15;
    int o = j * 16 + r;                  // original output index 0..255
    const float* src = (u ? Uw : Vw) + (size_t)o * FZ;
    for (int k = threadIdx.x; k < FZ; k += blockDim.x)
        Wc[(size_t)pr * FZ + k] = (bf16_t)src[k];
}

// ---------------- fused GEMM + gate + w-reduce -> partial logits ----------------
// 2048 blocks, 256 threads (4 waves, 2M x 2N, wave tile 64x64 of 32x32 frags)
__global__ __launch_bounds__(256, 3)
void gemm_gate(const float* __restrict__ x, const bf16_t* __restrict__ Wc,
               const float* __restrict__ Vb, const float* __restrict__ Ub,
               const float* __restrict__ ww, float* __restrict__ part) {
    __shared__ bf16_t As[BM * BK] __attribute__((aligned(16)));      // 16 KB, swizzled
    __shared__ bf16_t Bs[2][BN * BK] __attribute__((aligned(16)));   // 2x16 KB, swizzled

    // XCD-aware remap: the 4 n-blocks of one m-tile share bid%8 (same XCD L2)
    const int bid = blockIdx.x;
    const int nb = (bid >> 3) & 3;
    const int mt = (bid & 7) | ((bid >> 5) << 3);    // 0..511
    const int tid = threadIdx.x;
    const int l = tid & 63, wv = tid >> 6;           // lane, wave 0..3
    const int wm = wv >> 1, wn = wv & 1;             // 2M x 2N waves
    const int row0 = mt * BM;
    const int pcb = nb * BN;                         // packed-col base

    f32x16 acc[2][2] = {};
    float4 areg[8];                                  // A staging: 32 fp32/thread

    // --- A: issue global fp32 loads for tile t (coalesced: lane strides 32B) ---
    auto loadA = [&](int t) {
        int k0 = t * BK;
        #pragma unroll
        for (int i = 0; i < 4; ++i) {
            int row = i * 32 + (tid >> 3);           // 0..127
            const float* gp = x + (size_t)(row0 + row) * FZ + k0 + (tid & 7) * 8;
            areg[2 * i]     = *(const float4*)gp;
            areg[2 * i + 1] = *(const float4*)(gp + 4);
        }
    };
    // --- A: cvt + swizzled LDS write (slot q -> phys q^(row&7)) ---
    auto writeA = [&]() {
        #pragma unroll
        for (int i = 0; i < 4; ++i) {
            int row = i * 32 + (tid >> 3);
            int q = tid & 7;
            float4 f0 = areg[2 * i], f1 = areg[2 * i + 1];
            bf16x8 v;
            v[0] = (bf16_t)f0.x; v[1] = (bf16_t)f0.y; v[2] = (bf16_t)f0.z; v[3] = (bf16_t)f0.w;
            v[4] = (bf16_t)f1.x; v[5] = (bf16_t)f1.y; v[6] = (bf16_t)f1.z; v[7] = (bf16_t)f1.w;
            *(bf16x8*)&As[row * BK + (q ^ (row & 7)) * 8] = v;
        }
    };
    // --- B: global_load_lds, linear LDS dest + inverse-swizzled global source ---
    auto loadB = [&](int t, int buf) {
        int k0 = t * BK;
        #pragma unroll
        for (int cc = 0; cc < 4; ++cc) {
            int chunk = cc * 4 + wv;                 // 16 chunks of 1024 B
            int row = chunk * 8 + (l >> 3);          // LDS row this lane fills
            int ps = l & 7;                          // phys slot this lane fills
            const bf16_t* gp = Wc + (size_t)(pcb + row) * FZ + k0 + (ps ^ (row & 7)) * 8;
            bf16_t* lp = &Bs[buf][chunk * 512];      // wave-uniform base (+lane*16 in HW)
            __builtin_amdgcn_global_load_lds(
                (const __attribute__((address_space(1))) void*)gp,
                (__attribute__((address_space(3))) void*)lp, 16, 0, 0);
        }
    };

    // prologue: tile 0 fully staged
    loadA(0);
    loadB(0, 0);
    writeA();            // waits on A0 loads, converts, writes As
    __syncthreads();     // drains B0 DMA too

    for (int t = 0; t < NKT; ++t) {
        int cur = t & 1;
        // issue next tile's loads FIRST: latency hides under compute below
        if (t + 1 < NKT) {
            loadB(t + 1, cur ^ 1);   // async DMA into other B buffer
            loadA(t + 1);            // global -> regs
        }
        #pragma unroll
        for (int kk = 0; kk < 4; ++kk) {
            int ks = kk * 2 + (l >> 5);  // 16B k-slot for this lane
            bf16x8 af[2], bfr[2];
            #pragma unroll
            for (int fm = 0; fm < 2; ++fm) {
                int row = wm * 64 + fm * 32 + (l & 31);
                af[fm] = *(bf16x8*)&As[row * BK + (ks ^ (row & 7)) * 8];
            }
            #pragma unroll
            for (int fn = 0; fn < 2; ++fn) {
                int row = wn * 64 + fn * 32 + (l & 31);
                bfr[fn] = *(bf16x8*)&Bs[cur][row * BK + (ks ^ (row & 7)) * 8];
            }
            #pragma unroll
            for (int fm = 0; fm < 2; ++fm)
                #pragma unroll
                for (int fn = 0; fn < 2; ++fn)
                    acc[fm][fn] = __builtin_amdgcn_mfma_f32_32x32x16_bf16(
                        af[fm], bfr[fn], acc[fm][fn], 0, 0, 0);
        }
        __syncthreads();             // all waves done reading As/Bs[cur]; next loads drained
        if (t + 1 < NKT) {
            writeA();                // cvt + write As for tile t+1
            __syncthreads();         // As(t+1) visible to all waves
        }
    }

    // ---- epilogue: gate + reduce ----
    // C/D 32x32 layout: col = l&31, row = (e&3) + 8*(e>>2) + 4*(l>>5)
    const int col = l & 31;
    const int u = col >> 4;               // 0: V-half lane, 1: U-half lane
    float bias[2], wcf[2];
    #pragma unroll
    for (int fn = 0; fn < 2; ++fn) {
        int o = ((pcb + wn * 64 + fn * 32) >> 5) * 16 + (col & 15);
        bias[fn] = u ? Ub[o] : Vb[o];
        wcf[fn] = ww[o];
    }
    const int slot = nb * 2 + wn;         // 8 disjoint partial slots
    #pragma unroll
    for (int fm = 0; fm < 2; ++fm) {
        #pragma unroll
        for (int e = 0; e < 16; ++e) {
            float partial = 0.f;
            #pragma unroll
            for (int fn = 0; fn < 2; ++fn) {
                float z = acc[fm][fn][e] + bias[fn];
                float act = u ? (1.f / (1.f + expf(-z))) : tanhf(z);
                float pact = __shfl_xor(act, 16);     // partner half's activation
                partial += u ? 0.f : act * pact * wcf[fn];
            }
            partial += __shfl_xor(partial, 1);
            partial += __shfl_xor(partial, 2);
            partial += __shfl_xor(partial, 4);
            partial += __shfl_xor(partial, 8);
            if ((l & 31) == 0) {
                int r = row0 + wm * 64 + fm * 32 + (e & 3) + 8 * (e >> 2) + 4 * (l >> 5);
                part[(size_t)slot * M_TOTAL + r] = partial;
            }
        }
    }
}

// ---------------- per-bag masked softmax ----------------
__global__ __launch_bounds__(1024)
void softmax_kernel(const float* __restrict__ part, const int* __restrict__ nonpad,
                    float* __restrict__ out) {
    __shared__ float satt[PZ];
    __shared__ float red[16];
    int b = blockIdx.x;
    int np = nonpad[b];
    int tid = threadIdx.x;

    for (int p = tid; p < PZ; p += 1024) {
        float s = 0.f;
        #pragma unroll
        for (int q = 0; q < 8; ++q) s += part[(size_t)q * M_TOTAL + b * PZ + p];
        satt[p] = s;
    }
    __syncthreads();

    float m = -3.4e38f;
    for (int p = tid; p < np; p += 1024) m = fmaxf(m, satt[p]);
    #pragma unroll
    for (int off = 32; off; off >>= 1) m = fmaxf(m, __shfl_xor(m, off));
    if ((tid & 63) == 0) red[tid >> 6] = m;
    __syncthreads();
    m = red[0];
    #pragma unroll
    for (int i = 1; i < 16; ++i) m = fmaxf(m, red[i]);
    __syncthreads();

    float sum = 0.f;
    for (int p = tid; p < np; p += 1024) sum += expf(satt[p] - m);
    #pragma unroll
    for (int off = 32; off; off >>= 1) sum += __shfl_xor(sum, off);
    if ((tid & 63) == 0) red[tid >> 6] = sum;
    __syncthreads();
    float S = red[0];
    #pragma unroll
    for (int i = 1; i < 16; ++i) S += red[i];
    float inv = 1.f / S;

    for (int p = tid; p < PZ; p += 1024)
        out[b * PZ + p] = (p < np) ? expf(satt[p] - m) * inv : 0.f;
}

extern "C" void kernel_launch(void* const* d_in, const int* in_sizes, int n_in,
                              void* d_out, int out_size, void* d_ws, size_t ws_size,
                              hipStream_t stream) {
    const float* x   = (const float*)d_in[0];
    const int* nonpad = (const int*)d_in[1];
    const float* V_w = (const float*)d_in[2];
    const float* V_b = (const float*)d_in[3];
    const float* U_w = (const float*)d_in[4];
    const float* U_b = (const float*)d_in[5];
    const float* w_w = (const float*)d_in[6];
    // d_in[7] = w_b: uniform logit shift -> softmax-invariant, unused.

    bf16_t* Wc  = (bf16_t*)d_ws;                                  // 768 KB
    float* part = (float*)((char*)d_ws + (size_t)512 * FZ * 2);   // 2 MB
    float* out  = (float*)d_out;

    pack_weights<<<512, 128, 0, stream>>>(V_w, U_w, Wc);
    gemm_gate<<<2048, 256, 0, stream>>>(x, Wc, V_b, U_b, w_w, part);
    softmax_kernel<<<8, 1024, 0, stream>>>(part, nonpad, out);
}